// Round 13
// baseline (142.269 us; speedup 1.0000x reference)
//
#include <hip/hip_runtime.h>

// CRF loss: sum_b(forward_score[b] - gold_score[b]).  B=512, T=1024, L=32.
//
// R18 = R17 (constant-E, diagonal-at-pack) + VGPR-resident accumulator via
// safe in-place asm MFMA + f-broadcast read-ahead.
// Session model (R8b..R17): ~65% of SIMD cycles all-wave idle; VALU count
// (-28% -> -8% time), chain depth (R16b null), occupancy (R13b -10% at half),
// skew (R15b null) all weak. Remaining localized stalls:
//  (a) acc in AGPRs (VGPR_Count=60): ~16 v_accvgpr_read/step in the
//      post-MFMA serial segment + cross-file result latency.
//  (b) R17's 4x ds_read_b128 of the f-broadcast issued ~70cy before use vs
//      ~120cy LDS latency -> per-step lgkm wait.
// Fixes:
//  (a) single asm block, IN-PLACE accumulate: s_nop 1; mfma acc,Ea0,B0,acc;
//      mfma acc,Ea1,B1,acc; s_nop 7; s_nop 3  with "+v"(acc). No early-
//      clobber needed (zero-movs make acc live before inputs are read ->
//      RA guarantees disjoint regs; R13b's mov-storm came from "=&v" + a
//      separate 16-wide zc input - both eliminated; zc deleted). Zeroing
//      16 inline-0 movs sits BEFORE the MFMA, off the dependent path.
//      Hazard pads byte-identical to R13b (ran exact, absmax 0.0).
//  (b) f-broadcast single-buffer + read-ahead: publish f_{s+1}, ds_read it
//      back in the same step (per-wave DS ordering), consume next step
//      (~1 step of slack >> LDS latency).
//  VGPR diet: sm[] persistence dropped; scale results transient (t0/t1),
//  stored to shM only at the last step. Live set ~100 <= 128 (4 waves/SIMD).
// Renorm cadence/semantics identical to R17 (proven exact): measure at
// s%4==3 from unscaled acc[2] lane 0, exact 2^-e, fold into published f of
// s+1, last e un-applied. Gold preamble + wave-0 combine unchanged.

typedef float  f32x16 __attribute__((ext_vector_type(16)));
typedef short  s16x8  __attribute__((ext_vector_type(8)));
typedef float  f32x2  __attribute__((ext_vector_type(2)));
typedef float  f32x4  __attribute__((ext_vector_type(4)));

#define TT 1024
#define LL 32
#define BB 512
#define NC 8
#define CL 128
#define MS 33

union Frag { s16x8 v; unsigned u[4]; };

// pack two f32 -> u32 holding 2 bf16 (truncation): lo in [15:0], hi in [31:16]
__device__ __forceinline__ unsigned pack_bf16(float lo, float hi) {
    return __builtin_amdgcn_perm(__float_as_uint(hi), __float_as_uint(lo), 0x07060302u);
}

__global__ __launch_bounds__(NC * 64, 4) void crf_fused_kernel(
    const float* __restrict__ emission,    // [B, T, L]
    const int*   __restrict__ label_ids,   // [B, T]
    const float* __restrict__ transitions, // [L, L]
    float*       __restrict__ out)         // [1], pre-zeroed
{
    __shared__ __align__(16) float shM[NC][32 * MS];   // 33,792 B
    __shared__ __align__(16) float shF[NC][32];        // f broadcast (1 buf)
    __shared__ float shQ[2][64];
    __shared__ float tgArr[NC];
    __shared__ int   capArr[NC];

    const int tid  = threadIdx.x;
    const int w    = tid >> 6;             // wave id = chunk id
    const int lane = tid & 63;
    const int j    = lane & 31;            // A row / C-D col
    const int h    = lane >> 5;            // k-half
    const int b    = blockIdx.x;
    const int t0   = w * CL;

    const int*   labB = label_ids + b * TT + t0;
    const float* emB  = emission + ((size_t)b * TT + t0) * LL + j;

    // ---- gold score partial (transitions + emission gather), preamble ----
    {
        float g = 0.0f;
#pragma unroll
        for (int u = 0; u < 2; ++u) {
            int tt = t0 + 64 * u + lane;
            int l1 = labB[64 * u + lane];
            int l0 = (tt == 0) ? 0 : label_ids[b * TT + tt - 1];   // SOS at -1
            g += transitions[(l1 << 5) + l0];
            g += emission[((size_t)b * TT + tt) * LL + l1];
            if (tt == TT - 1) g += transitions[32 + l1];           // trans[END,last]
        }
#pragma unroll
        for (int m = 32; m >= 1; m >>= 1) g += __shfl_xor(g, m, 64);
        if (lane == 0) tgArr[w] = g;
    }

    // ---- E as CONSTANT A-frags, sigma k-order (built once) ----
    const float* trow = transitions + j * 32;
    Frag Ea0, Ea1;
#pragma unroll
    for (int p = 0; p < 4; ++p) {
        int c0 = ((2 * p) & 3)     + 8 * ((2 * p) >> 2)     + 4 * h;
        int c1 = ((2 * p + 1) & 3) + 8 * ((2 * p + 1) >> 2) + 4 * h;
        Ea0.u[p] = pack_bf16(__expf(trow[c0]),      __expf(trow[c1]));
        Ea1.u[p] = pack_bf16(__expf(trow[16 + c0]), __expf(trow[16 + c1]));
    }

    // ---- B = identity in sigma layout (M init; bf16 1.0 = 0x3F80) ----
    Frag B0, B1;
#pragma unroll
    for (int i = 0; i < 8; ++i) {
        int row = (i & 3) + 8 * (i >> 2) + 4 * h;
        B0.v[i] = (short)((row == j)      ? 0x3F80 : 0);
        B1.v[i] = (short)((row + 16 == j) ? 0x3F80 : 0);
    }

    f32x16 acc;

    float ring[8];
#pragma unroll
    for (int s = 0; s < 8; ++s) ring[s] = emB[s * LL];

    // publish f_0 and pre-read it (read-ahead pipeline prologue)
    shF[w][j] = __expf(ring[0]);
    const f32x4* fp = (const f32x4*)(&shF[w][0]);
    f32x4 fA = fp[h], fB = fp[2 + h], fC = fp[4 + h], fD = fp[6 + h];

    float sc = 1.0f;
    int   Cap = 0, elast = 0;

    // one recurrence step; refill only when told (tail has none)
    auto step = [&](int k, int s, bool refill, bool last) {
        // zero acc (off the dependent path), then in-place MFMA pair.
        //   s_nop 1      : VALU write -> MFMA src/C read (2 waits)
        //   mfma chain   : C accumulate fast path (0 waits)
        //   s_nop 7+3    : 16-pass MFMA D -> VALU/readlane read (~11 waits)
        // acc stays in ONE VGPR tuple forever: no accvgpr traffic.
#pragma unroll
        for (int i = 0; i < 16; ++i) acc[i] = 0.0f;
        asm volatile("s_nop 1\n\t"
                     "v_mfma_f32_32x32x16_bf16 %0, %1, %2, %0\n\t"
                     "v_mfma_f32_32x32x16_bf16 %0, %3, %4, %0\n\t"
                     "s_nop 7\n\t"
                     "s_nop 3"
                     : "+v"(acc)
                     : "v"(Ea0.v), "v"(B0.v), "v"(Ea1.v), "v"(B1.v));

        if ((s & 3) == 3) {                // renorm measure (unscaled proxy)
            int pb = __builtin_amdgcn_readlane(__float_as_int(acc[2]), 0);
            int e  = ((pb >> 23) & 0xff) - 127;
            sc = __int_as_float((127 - e) << 23);   // exact 2^-e
            Cap += e;
            elast = e;
        }

        // publish f_{s+1}, then read-ahead for next step (per-wave DS order
        // guarantees the read returns the just-published values).
        {
            float fn = __expf(ring[(k + 1) & 7]);
            if (((s + 1) & 3) == 0) fn *= sc;
            shF[w][j] = fn;
        }
        f32x4 nA = fp[h], nB = fp[2 + h], nC = fp[4 + h], nD = fp[6 + h];

        if (refill) ring[k] = emB[(s + 8) * LL];

        // scale by f_s (read ahead last step) + pack for the next link
        f32x2 t0v[4], t1v[4];
        {
            f32x2 fv, av;
            fv[0] = fA[0]; fv[1] = fA[1]; av[0] = acc[0];  av[1] = acc[1];  t0v[0] = fv * av;
            fv[0] = fA[2]; fv[1] = fA[3]; av[0] = acc[2];  av[1] = acc[3];  t0v[1] = fv * av;
            fv[0] = fB[0]; fv[1] = fB[1]; av[0] = acc[4];  av[1] = acc[5];  t0v[2] = fv * av;
            fv[0] = fB[2]; fv[1] = fB[3]; av[0] = acc[6];  av[1] = acc[7];  t0v[3] = fv * av;
            fv[0] = fC[0]; fv[1] = fC[1]; av[0] = acc[8];  av[1] = acc[9];  t1v[0] = fv * av;
            fv[0] = fC[2]; fv[1] = fC[3]; av[0] = acc[10]; av[1] = acc[11]; t1v[1] = fv * av;
            fv[0] = fD[0]; fv[1] = fD[1]; av[0] = acc[12]; av[1] = acc[13]; t1v[2] = fv * av;
            fv[0] = fD[2]; fv[1] = fD[3]; av[0] = acc[14]; av[1] = acc[15]; t1v[3] = fv * av;
        }
#pragma unroll
        for (int q = 0; q < 4; ++q) {
            B0.u[q] = pack_bf16(t0v[q][0], t0v[q][1]);
            B1.u[q] = pack_bf16(t1v[q][0], t1v[q][1]);
        }

        if (last) {                        // final M_c (scaled) -> shM
#pragma unroll
            for (int r = 0; r < 16; ++r) {
                int row = (r & 3) + 8 * (r >> 2) + 4 * h;
                float val = (r < 8) ? t0v[r >> 1][r & 1] : t1v[(r >> 1) - 4][r & 1];
                shM[w][row * MS + j] = val;
            }
        }

        fA = nA; fB = nB; fC = nC; fD = nD;
    };

    for (int s0 = 0; s0 < CL - 8; s0 += 8) {
#pragma unroll
        for (int k = 0; k < 8; ++k) step(k, s0 + k, true, false);
    }
#pragma unroll
    for (int k = 0; k < 8; ++k) step(k, CL - 8 + k, false, k == 7);

    Cap -= elast;                          // final measured e never applied
    if (lane == 0) capArr[w] = Cap;

    __syncthreads();

    // ---- wave 0: sequential 8-chunk matvec combine ----
    if (w == 0) {
        const float Eend = __expf(transitions[32 + j]);   // exp(trans[END][j])
        float q = (j == 0) ? 1.0f : 0.0f;                 // one-hot SOS
        int   Cq = 0;
        float gold = 0.0f;

#pragma unroll
        for (int c = 0; c < NC; ++c) {
            shQ[c & 1][lane] = q;
            asm volatile("s_waitcnt lgkmcnt(0)" ::: "memory");
            __builtin_amdgcn_wave_barrier();
            const float* Mrow = &shM[c][j * MS];
            const float* qv   = &shQ[c & 1][h * 32];
            float a0 = 0.f, a1 = 0.f, a2 = 0.f, a3 = 0.f;
#pragma unroll
            for (int i = 0; i < 32; i += 4) {
                a0 = fmaf(Mrow[i],     qv[i],     a0);
                a1 = fmaf(Mrow[i + 1], qv[i + 1], a1);
                a2 = fmaf(Mrow[i + 2], qv[i + 2], a2);
                a3 = fmaf(Mrow[i + 3], qv[i + 3], a3);
            }
            float qn = (a0 + a1) + (a2 + a3);
            int pb = __builtin_amdgcn_readlane(__float_as_int(qn), 2);
            int e  = ((pb >> 23) & 0xff) - 127;
            qn *= __int_as_float((127 - e) << 23);        // exact 2^-e
            Cq += e + capArr[c];
            gold += tgArr[c];
            q = qn;
        }

        float v = q * Eend;
#pragma unroll
        for (int m = 16; m >= 1; m >>= 1) v += __shfl_xor(v, m, 32);
        float fwd = __logf(v) + (float)Cq * 0.69314718055994531f;

        if (lane == 0) atomicAdd(out, fwd - gold);
    }
}

extern "C" void kernel_launch(void* const* d_in, const int* in_sizes, int n_in,
                              void* d_out, int out_size, void* d_ws, size_t ws_size,
                              hipStream_t stream)
{
    const float* emission    = (const float*)d_in[0];
    const int*   label_ids   = (const int*)d_in[1];
    const float* transitions = (const float*)d_in[2];
    float* out = (float*)d_out;

    (void)hipMemsetAsync(out, 0, sizeof(float), stream);
    crf_fused_kernel<<<BB, NC * 64, 0, stream>>>(emission, label_ids, transitions, out);
}

// Round 14
// 138.599 us; speedup vs baseline: 1.0265x; 1.0265x over previous
//
#include <hip/hip_runtime.h>

// CRF loss: sum_b(forward_score[b] - gold_score[b]).  B=512, T=1024, L=32.
//
// R19 = R17 lean step x DUAL independent chains per wave (convoy fix).
// Session ledger: R17 best (59-65us, ~42 VALU/step). Fixed residual: ~45% of
// slot cycles ALL-wave idle. Surviving explanation (consistent with R15b
// skew null): convoy re-locking - one-time skew decays, waves re-align at
// shared stall points (stall = attractor under round-robin issue). Fix must
// be structural: TWO chains per wave; compiler interleaves chain B's work
// into chain A's MFMA/LDS latency shadows at instruction level - immune to
// wave-scheduler convoying. R10's dual-chain failure mode (AGPR mov-storm)
// was fat-step (~65 VALU) + 128-reg cap; R19 uses the 35%-leaner R17 step
// and launch_bounds(256,2) -> 256-reg budget. Grid 512 x 256thr = 2 blk/CU
// = 2 waves/SIMD x 2 chains = same 4 chains/SIMD, pairwise-guaranteed ILP.
// Per-chain step is R17 verbatim (proven exact, absmax 0): constant-E
// A-frags, diagonal applied at the B-repack via per-chain 32-float LDS f
// broadcast (publish f_{s+1} mid-step, read at next step top, rho-slot
// f32x4 reads), renorm measure s%4==3 from unscaled acc[2] (exact 2^-e,
// folded into published f, last e un-applied), ring-8 refill + tail split.
// Block = 4 waves = 8 chunks; two-phase combine not needed (shM[8] fits);
// gold preamble covers 4 lane-passes/wave; wave-0 combine unchanged.

typedef float  f32x16 __attribute__((ext_vector_type(16)));
typedef short  s16x8  __attribute__((ext_vector_type(8)));
typedef float  f32x2  __attribute__((ext_vector_type(2)));
typedef float  f32x4  __attribute__((ext_vector_type(4)));

#define TT 1024
#define LL 32
#define BB 512
#define NW 4           // waves per block
#define CH 8           // chunks per block (2 per wave)
#define CL 128
#define MS 33

union Frag { s16x8 v; unsigned u[4]; };

// pack two f32 -> u32 holding 2 bf16 (truncation): lo in [15:0], hi in [31:16]
__device__ __forceinline__ unsigned pack_bf16(float lo, float hi) {
    return __builtin_amdgcn_perm(__float_as_uint(hi), __float_as_uint(lo), 0x07060302u);
}

__global__ __launch_bounds__(NW * 64, 2) void crf_fused_kernel(
    const float* __restrict__ emission,    // [B, T, L]
    const int*   __restrict__ label_ids,   // [B, T]
    const float* __restrict__ transitions, // [L, L]
    float*       __restrict__ out)         // [1], pre-zeroed
{
    __shared__ __align__(16) float shM[CH][32 * MS];   // 33,792 B
    __shared__ __align__(16) float shF[CH][32];        // per-chain f bcast
    __shared__ float shQ[2][64];
    __shared__ float tgArr[NW];
    __shared__ int   capArr[CH];

    const int tid  = threadIdx.x;
    const int w    = tid >> 6;             // wave id (0..3)
    const int lane = tid & 63;
    const int j    = lane & 31;            // A row / C-D col
    const int h    = lane >> 5;            // k-half
    const int b    = blockIdx.x;
    const int t0   = w * (2 * CL);         // 256 timesteps per wave

    // ---- gold score partial (transitions + emission gather), preamble ----
    {
        const int* labB = label_ids + b * TT + t0;
        float g = 0.0f;
#pragma unroll
        for (int u = 0; u < 4; ++u) {
            int tt = t0 + 64 * u + lane;
            int l1 = labB[64 * u + lane];
            int l0 = (tt == 0) ? 0 : label_ids[b * TT + tt - 1];   // SOS at -1
            g += transitions[(l1 << 5) + l0];
            g += emission[((size_t)b * TT + tt) * LL + l1];
            if (tt == TT - 1) g += transitions[32 + l1];           // trans[END,last]
        }
#pragma unroll
        for (int m = 32; m >= 1; m >>= 1) g += __shfl_xor(g, m, 64);
        if (lane == 0) tgArr[w] = g;
    }

    // ---- E as CONSTANT A-frags, sigma k-order (built once, shared) ----
    const float* trow = transitions + j * 32;
    Frag Ea0, Ea1;
#pragma unroll
    for (int p = 0; p < 4; ++p) {
        int c0 = ((2 * p) & 3)     + 8 * ((2 * p) >> 2)     + 4 * h;
        int c1 = ((2 * p + 1) & 3) + 8 * ((2 * p + 1) >> 2) + 4 * h;
        Ea0.u[p] = pack_bf16(__expf(trow[c0]),      __expf(trow[c1]));
        Ea1.u[p] = pack_bf16(__expf(trow[16 + c0]), __expf(trow[16 + c1]));
    }

    // ---- B = identity in sigma layout (M init), per chain ----
    Frag B0a, B1a, B0b, B1b;
#pragma unroll
    for (int i = 0; i < 8; ++i) {
        int row = (i & 3) + 8 * (i >> 2) + 4 * h;
        short lo = (short)((row == j)      ? 0x3F80 : 0);
        short hi = (short)((row + 16 == j) ? 0x3F80 : 0);
        B0a.v[i] = lo;  B1a.v[i] = hi;
        B0b.v[i] = lo;  B1b.v[i] = hi;
    }

    f32x16 zc, accA, accB;
#pragma unroll
    for (int i = 0; i < 16; ++i) zc[i] = 0.0f;

    const float* emA  = emission + ((size_t)b * TT + t0) * LL + j;
    const float* emBp = emA + (size_t)CL * LL;     // chain B: t0 + 128

    float ringA[8], ringB[8];
#pragma unroll
    for (int s = 0; s < 8; ++s) { ringA[s] = emA[s * LL]; ringB[s] = emBp[s * LL]; }

    // publish f_0 for both chains
    shF[2 * w][j]     = __expf(ringA[0]);
    shF[2 * w + 1][j] = __expf(ringB[0]);

    float scA = 1.0f, scB = 1.0f;
    int   CapA = 0, elA = 0, CapB = 0, elB = 0;

    // one recurrence step on one chain (R17 form, proven exact)
    auto step = [&](Frag& B0, Frag& B1, f32x16& acc, float (&ring)[8],
                    float& sc, int& Cap, int& elast, const float* em,
                    float* shFc, int cidx, int k, int s, bool refill, bool last) {
        // f_s broadcast (published one step ago) at rho-slot offsets
        const f32x4* fp = (const f32x4*)shFc;
        f32x4 fA = fp[h], fB = fp[2 + h], fC = fp[4 + h], fD = fp[6 + h];

        // E*M with constant A-frags (builtin: compiler-scheduled hazards)
        acc = __builtin_amdgcn_mfma_f32_32x32x16_bf16(Ea0.v, B0.v, zc, 0, 0, 0);
        acc = __builtin_amdgcn_mfma_f32_32x32x16_bf16(Ea1.v, B1.v, acc, 0, 0, 0);

        if ((s & 3) == 3) {                // renorm measure (unscaled proxy)
            int pb = __builtin_amdgcn_readlane(__float_as_int(acc[2]), 0);
            int e  = ((pb >> 23) & 0xff) - 127;
            sc = __int_as_float((127 - e) << 23);   // exact 2^-e
            Cap += e;
            elast = e;
        }

        // publish f_{s+1} (ring slot (k+1)&7 holds timestep s+1)
        {
            float fn = __expf(ring[(k + 1) & 7]);
            if (((s + 1) & 3) == 0) fn *= sc;
            shFc[j] = fn;
        }

        if (refill) ring[k] = em[(s + 8) * LL];

        // scale by f_s + pack for the next link
        f32x2 t0v[4], t1v[4];
        {
            f32x2 fv, av;
            fv[0] = fA[0]; fv[1] = fA[1]; av[0] = acc[0];  av[1] = acc[1];  t0v[0] = fv * av;
            fv[0] = fA[2]; fv[1] = fA[3]; av[0] = acc[2];  av[1] = acc[3];  t0v[1] = fv * av;
            fv[0] = fB[0]; fv[1] = fB[1]; av[0] = acc[4];  av[1] = acc[5];  t0v[2] = fv * av;
            fv[0] = fB[2]; fv[1] = fB[3]; av[0] = acc[6];  av[1] = acc[7];  t0v[3] = fv * av;
            fv[0] = fC[0]; fv[1] = fC[1]; av[0] = acc[8];  av[1] = acc[9];  t1v[0] = fv * av;
            fv[0] = fC[2]; fv[1] = fC[3]; av[0] = acc[10]; av[1] = acc[11]; t1v[1] = fv * av;
            fv[0] = fD[0]; fv[1] = fD[1]; av[0] = acc[12]; av[1] = acc[13]; t1v[2] = fv * av;
            fv[0] = fD[2]; fv[1] = fD[3]; av[0] = acc[14]; av[1] = acc[15]; t1v[3] = fv * av;
        }
#pragma unroll
        for (int q = 0; q < 4; ++q) {
            B0.u[q] = pack_bf16(t0v[q][0], t0v[q][1]);
            B1.u[q] = pack_bf16(t1v[q][0], t1v[q][1]);
        }

        if (last) {                        // final M_c (scaled) -> shM
#pragma unroll
            for (int r = 0; r < 16; ++r) {
                int row = (r & 3) + 8 * (r >> 2) + 4 * h;
                float val = (r < 8) ? t0v[r >> 1][r & 1] : t1v[(r >> 1) - 4][r & 1];
                shM[cidx][row * MS + j] = val;
            }
        }
    };

    for (int s0 = 0; s0 < CL - 8; s0 += 8) {
#pragma unroll
        for (int k = 0; k < 8; ++k) {
            step(B0a, B1a, accA, ringA, scA, CapA, elA, emA,
                 &shF[2 * w][0],     2 * w,     k, s0 + k, true, false);
            step(B0b, B1b, accB, ringB, scB, CapB, elB, emBp,
                 &shF[2 * w + 1][0], 2 * w + 1, k, s0 + k, true, false);
        }
    }
#pragma unroll
    for (int k = 0; k < 8; ++k) {
        step(B0a, B1a, accA, ringA, scA, CapA, elA, emA,
             &shF[2 * w][0],     2 * w,     k, CL - 8 + k, false, k == 7);
        step(B0b, B1b, accB, ringB, scB, CapB, elB, emBp,
             &shF[2 * w + 1][0], 2 * w + 1, k, CL - 8 + k, false, k == 7);
    }

    CapA -= elA;                           // final measured e never applied
    CapB -= elB;
    if (lane == 0) { capArr[2 * w] = CapA; capArr[2 * w + 1] = CapB; }

    __syncthreads();

    // ---- wave 0: sequential 8-chunk matvec combine ----
    if (w == 0) {
        const float Eend = __expf(transitions[32 + j]);   // exp(trans[END][j])
        float q = (j == 0) ? 1.0f : 0.0f;                 // one-hot SOS
        int   Cq = 0;

#pragma unroll
        for (int c = 0; c < CH; ++c) {
            shQ[c & 1][lane] = q;
            asm volatile("s_waitcnt lgkmcnt(0)" ::: "memory");
            __builtin_amdgcn_wave_barrier();
            const float* Mrow = &shM[c][j * MS];
            const float* qv   = &shQ[c & 1][h * 32];
            float a0 = 0.f, a1 = 0.f, a2 = 0.f, a3 = 0.f;
#pragma unroll
            for (int i = 0; i < 32; i += 4) {
                a0 = fmaf(Mrow[i],     qv[i],     a0);
                a1 = fmaf(Mrow[i + 1], qv[i + 1], a1);
                a2 = fmaf(Mrow[i + 2], qv[i + 2], a2);
                a3 = fmaf(Mrow[i + 3], qv[i + 3], a3);
            }
            float qn = (a0 + a1) + (a2 + a3);
            int pb = __builtin_amdgcn_readlane(__float_as_int(qn), 2);
            int e  = ((pb >> 23) & 0xff) - 127;
            qn *= __int_as_float((127 - e) << 23);        // exact 2^-e
            Cq += e + capArr[c];
            q = qn;
        }

        float gold = 0.0f;
#pragma unroll
        for (int c = 0; c < NW; ++c) gold += tgArr[c];

        float v = q * Eend;
#pragma unroll
        for (int m = 16; m >= 1; m >>= 1) v += __shfl_xor(v, m, 32);
        float fwd = __logf(v) + (float)Cq * 0.69314718055994531f;

        if (lane == 0) atomicAdd(out, fwd - gold);
    }
}

extern "C" void kernel_launch(void* const* d_in, const int* in_sizes, int n_in,
                              void* d_out, int out_size, void* d_ws, size_t ws_size,
                              hipStream_t stream)
{
    const float* emission    = (const float*)d_in[0];
    const int*   label_ids   = (const int*)d_in[1];
    const float* transitions = (const float*)d_in[2];
    float* out = (float*)d_out;

    (void)hipMemsetAsync(out, 0, sizeof(float), stream);
    crf_fused_kernel<<<BB, NW * 64, 0, stream>>>(emission, label_ids, transitions, out);
}

// Round 15
// 138.542 us; speedup vs baseline: 1.0269x; 1.0004x over previous
//
#include <hip/hip_runtime.h>

// CRF loss: sum_b(forward_score[b] - gold_score[b]).  B=512, T=1024, L=32.
//
// R20 = dual-chain (R19 step) x HALF chain length: 8 waves x 2 chains x 64.
// Session model, triangulated (R8b/R13b/R17/R19):
//   wall = bodies_per_wave x cyc_per_body(ILP);  residency nearly free
//   (R13b: half waves -> +9%), ILP-2 runs 2 bodies in 1.24x one body's
//   latency (R19: 620 vs 1100 cyc/body). R19 was null ONLY because
//   bodies/wave doubled as per-body halved. This round: keep ILP-2, halve
//   bodies/wave: 16 chunks of 64 steps, 2 per wave -> 128 bodies/wave at
//   ~620 cyc -> predict ~79k cyc ~ 33-40us kernel.
// Geometry: 512-thr blocks, 8 waves; wave w runs chunks 2w (t0..t0+63) and
// 2w+1; per-chain state/step identical to R19 (R17 lean form, proven exact):
// constant-E A-frags, diagonal at B-repack via per-chain 32-float LDS f
// broadcast, renorm s%4==3 (exact 2^-e, elast un-applied), ring-8 + tail.
// launch_bounds(512,4): same cap as R10/R19 dual-chain binaries (56-60 VGPR,
// no spill, 2 blk/CU). Final scaled M persists in sm regs; 16 chunks ->
// two-phase combine over 8 LDS slots (R10-proven): waves 0-3 deposit
// chunks 0..7 -> wave0 folds -> waves 4-7 deposit 8..15 -> wave0 folds.
// Gold preamble: 2 lane-passes per wave (128 timesteps). Combine unchanged.

typedef float  f32x16 __attribute__((ext_vector_type(16)));
typedef short  s16x8  __attribute__((ext_vector_type(8)));
typedef float  f32x2  __attribute__((ext_vector_type(2)));
typedef float  f32x4  __attribute__((ext_vector_type(4)));

#define TT 1024
#define LL 32
#define BB 512
#define NW 8           // waves per block
#define CH 16          // chunks per block (2 per wave)
#define CL 64          // steps per chain
#define NS 8           // LDS combine slots per phase
#define MS 33

union Frag { s16x8 v; unsigned u[4]; };

// pack two f32 -> u32 holding 2 bf16 (truncation): lo in [15:0], hi in [31:16]
__device__ __forceinline__ unsigned pack_bf16(float lo, float hi) {
    return __builtin_amdgcn_perm(__float_as_uint(hi), __float_as_uint(lo), 0x07060302u);
}

__global__ __launch_bounds__(NW * 64, 4) void crf_fused_kernel(
    const float* __restrict__ emission,    // [B, T, L]
    const int*   __restrict__ label_ids,   // [B, T]
    const float* __restrict__ transitions, // [L, L]
    float*       __restrict__ out)         // [1], pre-zeroed
{
    __shared__ __align__(16) float shM[NS][32 * MS];   // 33,792 B
    __shared__ __align__(16) float shF[CH][32];        // per-chain f bcast
    __shared__ float shQ[2][64];
    __shared__ float tgArr[NW];
    __shared__ int   capArr[CH];

    const int tid  = threadIdx.x;
    const int w    = tid >> 6;             // wave id (0..7)
    const int lane = tid & 63;
    const int j    = lane & 31;            // A row / C-D col
    const int h    = lane >> 5;            // k-half
    const int b    = blockIdx.x;
    const int t0   = w * (2 * CL);         // 128 timesteps per wave

    // ---- gold score partial (transitions + emission gather), preamble ----
    {
        const int* labB = label_ids + b * TT + t0;
        float g = 0.0f;
#pragma unroll
        for (int u = 0; u < 2; ++u) {
            int tt = t0 + 64 * u + lane;
            int l1 = labB[64 * u + lane];
            int l0 = (tt == 0) ? 0 : label_ids[b * TT + tt - 1];   // SOS at -1
            g += transitions[(l1 << 5) + l0];
            g += emission[((size_t)b * TT + tt) * LL + l1];
            if (tt == TT - 1) g += transitions[32 + l1];           // trans[END,last]
        }
#pragma unroll
        for (int m = 32; m >= 1; m >>= 1) g += __shfl_xor(g, m, 64);
        if (lane == 0) tgArr[w] = g;
    }

    // ---- E as CONSTANT A-frags, sigma k-order (built once, shared) ----
    const float* trow = transitions + j * 32;
    Frag Ea0, Ea1;
#pragma unroll
    for (int p = 0; p < 4; ++p) {
        int c0 = ((2 * p) & 3)     + 8 * ((2 * p) >> 2)     + 4 * h;
        int c1 = ((2 * p + 1) & 3) + 8 * ((2 * p + 1) >> 2) + 4 * h;
        Ea0.u[p] = pack_bf16(__expf(trow[c0]),      __expf(trow[c1]));
        Ea1.u[p] = pack_bf16(__expf(trow[16 + c0]), __expf(trow[16 + c1]));
    }

    // ---- B = identity in sigma layout (M init), per chain ----
    Frag B0a, B1a, B0b, B1b;
#pragma unroll
    for (int i = 0; i < 8; ++i) {
        int row = (i & 3) + 8 * (i >> 2) + 4 * h;
        short lo = (short)((row == j)      ? 0x3F80 : 0);
        short hi = (short)((row + 16 == j) ? 0x3F80 : 0);
        B0a.v[i] = lo;  B1a.v[i] = hi;
        B0b.v[i] = lo;  B1b.v[i] = hi;
    }

    f32x16 zc, accA, accB;
#pragma unroll
    for (int i = 0; i < 16; ++i) zc[i] = 0.0f;

    const float* emA  = emission + ((size_t)b * TT + t0) * LL + j;
    const float* emBp = emA + (size_t)CL * LL;     // chain B: t0 + 64

    float ringA[8], ringB[8];
#pragma unroll
    for (int s = 0; s < 8; ++s) { ringA[s] = emA[s * LL]; ringB[s] = emBp[s * LL]; }

    // publish f_0 for both chains
    shF[2 * w][j]     = __expf(ringA[0]);
    shF[2 * w + 1][j] = __expf(ringB[0]);

    float scA = 1.0f, scB = 1.0f;
    int   CapA = 0, elA = 0, CapB = 0, elB = 0;
    f32x2 smA0[4], smA1[4], smB0[4], smB1[4];      // final scaled M per chain

    // one recurrence step on one chain (R17/R19 lean form, proven exact)
    auto step = [&](Frag& B0, Frag& B1, f32x16& acc, float (&ring)[8],
                    float& sc, int& Cap, int& elast, const float* em,
                    float* shFc, f32x2 (&sm0)[4], f32x2 (&sm1)[4],
                    int k, int s, bool refill, bool last) {
        // f_s broadcast (published one step ago) at rho-slot offsets
        const f32x4* fp = (const f32x4*)shFc;
        f32x4 fA = fp[h], fB = fp[2 + h], fC = fp[4 + h], fD = fp[6 + h];

        // E*M with constant A-frags
        acc = __builtin_amdgcn_mfma_f32_32x32x16_bf16(Ea0.v, B0.v, zc, 0, 0, 0);
        acc = __builtin_amdgcn_mfma_f32_32x32x16_bf16(Ea1.v, B1.v, acc, 0, 0, 0);

        if ((s & 3) == 3) {                // renorm measure (unscaled proxy)
            int pb = __builtin_amdgcn_readlane(__float_as_int(acc[2]), 0);
            int e  = ((pb >> 23) & 0xff) - 127;
            sc = __int_as_float((127 - e) << 23);   // exact 2^-e
            Cap += e;
            elast = e;
        }

        // publish f_{s+1} (ring slot (k+1)&7 holds timestep s+1)
        {
            float fn = __expf(ring[(k + 1) & 7]);
            if (((s + 1) & 3) == 0) fn *= sc;
            shFc[j] = fn;
        }

        if (refill) ring[k] = em[(s + 8) * LL];

        // scale by f_s + pack for the next link
        f32x2 t0v[4], t1v[4];
        {
            f32x2 fv, av;
            fv[0] = fA[0]; fv[1] = fA[1]; av[0] = acc[0];  av[1] = acc[1];  t0v[0] = fv * av;
            fv[0] = fA[2]; fv[1] = fA[3]; av[0] = acc[2];  av[1] = acc[3];  t0v[1] = fv * av;
            fv[0] = fB[0]; fv[1] = fB[1]; av[0] = acc[4];  av[1] = acc[5];  t0v[2] = fv * av;
            fv[0] = fB[2]; fv[1] = fB[3]; av[0] = acc[6];  av[1] = acc[7];  t0v[3] = fv * av;
            fv[0] = fC[0]; fv[1] = fC[1]; av[0] = acc[8];  av[1] = acc[9];  t1v[0] = fv * av;
            fv[0] = fC[2]; fv[1] = fC[3]; av[0] = acc[10]; av[1] = acc[11]; t1v[1] = fv * av;
            fv[0] = fD[0]; fv[1] = fD[1]; av[0] = acc[12]; av[1] = acc[13]; t1v[2] = fv * av;
            fv[0] = fD[2]; fv[1] = fD[3]; av[0] = acc[14]; av[1] = acc[15]; t1v[3] = fv * av;
        }
#pragma unroll
        for (int q = 0; q < 4; ++q) {
            B0.u[q] = pack_bf16(t0v[q][0], t0v[q][1]);
            B1.u[q] = pack_bf16(t1v[q][0], t1v[q][1]);
        }

        if (last) {                        // persist final scaled M in regs
#pragma unroll
            for (int q = 0; q < 4; ++q) { sm0[q] = t0v[q]; sm1[q] = t1v[q]; }
        }
    };

    for (int s0 = 0; s0 < CL - 8; s0 += 8) {
#pragma unroll
        for (int k = 0; k < 8; ++k) {
            step(B0a, B1a, accA, ringA, scA, CapA, elA, emA,
                 &shF[2 * w][0],     smA0, smA1, k, s0 + k, true, false);
            step(B0b, B1b, accB, ringB, scB, CapB, elB, emBp,
                 &shF[2 * w + 1][0], smB0, smB1, k, s0 + k, true, false);
        }
    }
#pragma unroll
    for (int k = 0; k < 8; ++k) {
        step(B0a, B1a, accA, ringA, scA, CapA, elA, emA,
             &shF[2 * w][0],     smA0, smA1, k, CL - 8 + k, false, k == 7);
        step(B0b, B1b, accB, ringB, scB, CapB, elB, emBp,
             &shF[2 * w + 1][0], smB0, smB1, k, CL - 8 + k, false, k == 7);
    }

    CapA -= elA;                           // final measured e never applied
    CapB -= elB;
    if (lane == 0) { capArr[2 * w] = CapA; capArr[2 * w + 1] = CapB; }

    // deposit one chain's final M into an LDS slot
    auto deposit = [&](int slot, f32x2 (&sm0)[4], f32x2 (&sm1)[4]) {
#pragma unroll
        for (int r = 0; r < 16; ++r) {
            int row = (r & 3) + 8 * (r >> 2) + 4 * h;
            float val = (r < 8) ? sm0[r >> 1][r & 1] : sm1[(r >> 1) - 4][r & 1];
            shM[slot][row * MS + j] = val;
        }
    };

    // wave-0 combine state (persists across both phases)
    const float Eend = __expf(transitions[32 + j]);   // exp(trans[END][j])
    float q  = (j == 0) ? 1.0f : 0.0f;                // one-hot SOS
    int   Cq = 0;

    auto combine8 = [&](int base) {
#pragma unroll
        for (int c = 0; c < NS; ++c) {
            shQ[c & 1][lane] = q;
            asm volatile("s_waitcnt lgkmcnt(0)" ::: "memory");
            __builtin_amdgcn_wave_barrier();
            const float* Mrow = &shM[c][j * MS];
            const float* qv   = &shQ[c & 1][h * 32];
            float a0 = 0.f, a1 = 0.f, a2 = 0.f, a3 = 0.f;
#pragma unroll
            for (int i = 0; i < 32; i += 4) {
                a0 = fmaf(Mrow[i],     qv[i],     a0);
                a1 = fmaf(Mrow[i + 1], qv[i + 1], a1);
                a2 = fmaf(Mrow[i + 2], qv[i + 2], a2);
                a3 = fmaf(Mrow[i + 3], qv[i + 3], a3);
            }
            float qn = (a0 + a1) + (a2 + a3);
            int pb = __builtin_amdgcn_readlane(__float_as_int(qn), 2);
            int e  = ((pb >> 23) & 0xff) - 127;
            qn *= __int_as_float((127 - e) << 23);        // exact 2^-e
            Cq += e + capArr[base + c];
            q = qn;
        }
    };

    // ---- phase A: waves 0-3 deposit chunks 0..7 ----
    if (w < 4) { deposit(2 * w, smA0, smA1); deposit(2 * w + 1, smB0, smB1); }

    __syncthreads();

    if (w == 0) combine8(0);               // fold chunks 0..7

    __syncthreads();

    // ---- phase B: waves 4-7 deposit chunks 8..15 into the same slots ----
    if (w >= 4) { deposit(2 * (w - 4), smA0, smA1); deposit(2 * (w - 4) + 1, smB0, smB1); }

    __syncthreads();

    if (w == 0) {
        combine8(NS);                      // fold chunks 8..15

        float gold = 0.0f;
#pragma unroll
        for (int c = 0; c < NW; ++c) gold += tgArr[c];

        float v = q * Eend;
#pragma unroll
        for (int m = 16; m >= 1; m >>= 1) v += __shfl_xor(v, m, 32);
        float fwd = __logf(v) + (float)Cq * 0.69314718055994531f;

        if (lane == 0) atomicAdd(out, fwd - gold);
    }
}

extern "C" void kernel_launch(void* const* d_in, const int* in_sizes, int n_in,
                              void* d_out, int out_size, void* d_ws, size_t ws_size,
                              hipStream_t stream)
{
    const float* emission    = (const float*)d_in[0];
    const int*   label_ids   = (const int*)d_in[1];
    const float* transitions = (const float*)d_in[2];
    float* out = (float*)d_out;

    (void)hipMemsetAsync(out, 0, sizeof(float), stream);
    crf_fused_kernel<<<BB, NW * 64, 0, stream>>>(emission, label_ids, transitions, out);
}